// Round 5
// baseline (4612.465 us; speedup 1.0000x reference)
//
#include <hip/hip_runtime.h>

#define BATCH 8
#define SEQ   4096
#define DIM   512

typedef __attribute__((ext_vector_type(8))) short bf16x8;
typedef __attribute__((ext_vector_type(4))) float f32x4;
typedef __attribute__((ext_vector_type(4))) unsigned short us16x4;

__device__ __forceinline__ unsigned short f2bf(float f) {
  unsigned int u = __float_as_uint(f);
  unsigned int r = (u + 0x7fffu + ((u >> 16) & 1u)) >> 16;
  return (unsigned short)r;
}
__device__ __forceinline__ float bf2f(unsigned short s) {
  return __uint_as_float(((unsigned int)s) << 16);
}

// ---------------------------------------------------------------------------
// Transpose + split weights: Wt[e][d] = W[d][e] (* scale for rotation).
// ---------------------------------------------------------------------------
__global__ __launch_bounds__(256) void wt_split_kernel(
    const float* __restrict__ rot, const float* __restrict__ ent,
    unsigned short* __restrict__ wrh, unsigned short* __restrict__ wrl,
    unsigned short* __restrict__ weh, unsigned short* __restrict__ wel) {
  const float scale = 0.04419417382415922f;  // 1/sqrt(512)
  int g = blockIdx.x * 256 + threadIdx.x;
  for (int idx = g; idx < 512 * 512; idx += 128 * 256) {
    int d = idx >> 9, e = idx & 511;
    size_t o = (size_t)e * 512 + d;
    float v = rot[idx] * scale;
    unsigned short h = f2bf(v);
    wrh[o] = h; wrl[o] = f2bf(v - bf2f(h));
    float v2 = ent[idx];
    unsigned short h2 = f2bf(v2);
    weh[o] = h2; wel[o] = f2bf(v2 - bf2f(h2));
  }
}

// ---------------------------------------------------------------------------
// Row-major split of x into bf16 hi/lo (for proj_both A-fragments).
// ---------------------------------------------------------------------------
__global__ __launch_bounds__(256) void x_split_kernel(
    const float* __restrict__ X, unsigned short* __restrict__ Xh,
    unsigned short* __restrict__ Xl) {
  size_t i = ((size_t)blockIdx.x * 256 + threadIdx.x) * 4;
  float4 v = *(const float4*)(X + i);
  us16x4 hh, ll;
  float vv[4] = {v.x, v.y, v.z, v.w};
#pragma unroll
  for (int e = 0; e < 4; ++e) {
    unsigned short h = f2bf(vv[e]);
    hh[e] = h;
    ll[e] = f2bf(vv[e] - bf2f(h));
  }
  *(us16x4*)(Xh + i) = hh;
  *(us16x4*)(Xl + i) = ll;
}

// ---------------------------------------------------------------------------
// Transpose x: Xt[b][d][n] = x[b][n][d], bf16 hi only (PV is single-term).
// ---------------------------------------------------------------------------
__global__ __launch_bounds__(256) void xt_split_kernel(
    const float* __restrict__ X, unsigned short* __restrict__ Th) {
  __shared__ float T[64][65];
  const int b = blockIdx.z, n0 = blockIdx.x * 64, d0 = blockIdx.y * 64;
  const int tid = threadIdx.x;
  for (int idx = tid; idx < 4096; idx += 256) {
    int r = idx >> 6, c = idx & 63;
    T[r][c] = X[((size_t)(b * SEQ + n0 + r)) * DIM + d0 + c];
  }
  __syncthreads();
  for (int idx = tid; idx < 4096; idx += 256) {
    int r = idx >> 6, c = idx & 63;  // r: d, c: n
    size_t o = ((size_t)(b * DIM + d0 + r)) * SEQ + n0 + c;
    Th[o] = f2bf(T[c][r]);
  }
}

// ---------------------------------------------------------------------------
// Fused projection: Q = X@rot*scale, K = X@ent via bf16-split MFMA (3 terms).
// A-fragments read directly from pre-split Xh/Xl.
// ---------------------------------------------------------------------------
__global__ __launch_bounds__(256, 2) void proj_both(
    const unsigned short* __restrict__ Xh, const unsigned short* __restrict__ Xl,
    const unsigned short* __restrict__ wrh, const unsigned short* __restrict__ wrl,
    const unsigned short* __restrict__ weh, const unsigned short* __restrict__ wel,
    unsigned short* __restrict__ qh, unsigned short* __restrict__ ql,
    unsigned short* __restrict__ kh, unsigned short* __restrict__ kl) {
  const int tid = threadIdx.x;
  const int w = tid >> 6, lane = tid & 63, l15 = lane & 15, quad = lane >> 4;
  const int rowBase = blockIdx.y * 64 + (w & 1) * 32;
  const int colBase = blockIdx.x * 64 + (w >> 1) * 32;
  f32x4 qa[2][2] = {}, ka[2][2] = {};
  size_t xo[2];
  const unsigned short *rh[2], *rl[2], *eh[2], *el[2];
  xo[0] = (size_t)(rowBase + l15) * DIM + quad * 8;
  xo[1] = (size_t)(rowBase + 16 + l15) * DIM + quad * 8;
#pragma unroll
  for (int ni = 0; ni < 2; ++ni) {
    size_t o = (size_t)(colBase + ni * 16 + l15) * DIM + quad * 8;
    rh[ni] = wrh + o; rl[ni] = wrl + o; eh[ni] = weh + o; el[ni] = wel + o;
  }
  for (int d0 = 0; d0 < DIM; d0 += 32) {
    bf16x8 ah[2], al[2];
#pragma unroll
    for (int mi = 0; mi < 2; ++mi) {
      ah[mi] = *(const bf16x8*)(Xh + xo[mi] + d0);
      al[mi] = *(const bf16x8*)(Xl + xo[mi] + d0);
    }
#pragma unroll
    for (int ni = 0; ni < 2; ++ni) {
      bf16x8 bh = *(const bf16x8*)(rh[ni] + d0);
      bf16x8 bl = *(const bf16x8*)(rl[ni] + d0);
      bf16x8 ch = *(const bf16x8*)(eh[ni] + d0);
      bf16x8 cl = *(const bf16x8*)(el[ni] + d0);
#pragma unroll
      for (int mi = 0; mi < 2; ++mi) {
        qa[mi][ni] = __builtin_amdgcn_mfma_f32_16x16x32_bf16(ah[mi], bh, qa[mi][ni], 0, 0, 0);
        qa[mi][ni] = __builtin_amdgcn_mfma_f32_16x16x32_bf16(ah[mi], bl, qa[mi][ni], 0, 0, 0);
        qa[mi][ni] = __builtin_amdgcn_mfma_f32_16x16x32_bf16(al[mi], bh, qa[mi][ni], 0, 0, 0);
        ka[mi][ni] = __builtin_amdgcn_mfma_f32_16x16x32_bf16(ah[mi], ch, ka[mi][ni], 0, 0, 0);
        ka[mi][ni] = __builtin_amdgcn_mfma_f32_16x16x32_bf16(ah[mi], cl, ka[mi][ni], 0, 0, 0);
        ka[mi][ni] = __builtin_amdgcn_mfma_f32_16x16x32_bf16(al[mi], ch, ka[mi][ni], 0, 0, 0);
      }
    }
  }
#pragma unroll
  for (int mi = 0; mi < 2; ++mi)
#pragma unroll
    for (int ni = 0; ni < 2; ++ni)
#pragma unroll
      for (int r = 0; r < 4; ++r) {
        int row = rowBase + mi * 16 + quad * 4 + r;
        int col = colBase + ni * 16 + l15;
        size_t o = (size_t)row * DIM + col;
        float v = qa[mi][ni][r];
        unsigned short h = f2bf(v);
        qh[o] = h; ql[o] = f2bf(v - bf2f(h));
        float v2 = ka[mi][ni][r];
        unsigned short h2 = f2bf(v2);
        kh[o] = h2; kl[o] = f2bf(v2 - bf2f(h2));
      }
}

// ---------------------------------------------------------------------------
// Flash attention. BQ=128, BK=64, 512 threads (8 waves), 2 blocks/CU.
// S-stage: wave w -> q-subs {2(w&3),+1}, k-subs {2(w>>2),+1}.
// Staging: Qh/Ql 128x32, Kh/Kl 64x32 per 32-d chunk, double-buffered,
// swizzle swz=(r>>1)&3 (2-way max = free). 1 barrier per chunk.
// PV: wave w owns d-slice [w*64, w*64+64), single-term P@x.
// Split-K via gridDim.z; merge_kernel combines.
// ---------------------------------------------------------------------------
__global__ __launch_bounds__(512, 4) void attn_mfma(
    const unsigned short* __restrict__ Qh, const unsigned short* __restrict__ Ql,
    const unsigned short* __restrict__ Kh, const unsigned short* __restrict__ Kl,
    const unsigned short* __restrict__ Xth, float* __restrict__ out,
    float* __restrict__ Opart, float* __restrict__ Mp, float* __restrict__ Lp) {
  // buffer layout (shorts): Qh[0..4095] Ql[4096..8191] Kh[8192..10239] Kl[10240..12287]
  __shared__ short stage[2][12288];        // 48 KiB
  __shared__ unsigned short PsH[128][72];  // 18 KiB
  __shared__ float red1[128][2], red2[128][2];
  __shared__ float m_s[128], l_s[128], al_s[128];

  const int tid = threadIdx.x;
  const int w = tid >> 6, lane = tid & 63, l15 = lane & 15, quad = lane >> 4;
  const int b = blockIdx.y, q0 = blockIdx.x * 128;
  const int qsp = (w & 3) * 2, ksp = (w >> 2) * 2;
  const int ktiles = (SEQ / 64) / gridDim.z;
  const int kbase = blockIdx.z * ktiles * 64;

  if (tid < 128) { m_s[tid] = -3.0e38f; l_s[tid] = 0.0f; }
  __syncthreads();

  f32x4 Of[8][4] = {};

  // staging geometry
  const int sr = lane >> 2, scm = lane & 3;
  const int jblk = scm ^ ((sr >> 1) & 3);            // logical 16B block to load
  const bool isQ = (w < 4);
  const int rbase = isQ ? (w & 1) * 64 : ((w >> 1) & 1) * 32;
  const int ninst = isQ ? 4 : 2;
  const int plane_off = isQ ? ((w >> 1) & 1) * 4096 : 8192 + (w & 1) * 2048;
  const unsigned short* gQ = (((w >> 1) & 1) ? Ql : Qh) + (size_t)(b * SEQ + q0) * DIM;
  const unsigned short* gK = ((w & 1) ? Kl : Kh) + (size_t)b * SEQ * DIM;
  const int pb = (quad ^ ((l15 >> 1) & 3)) * 8;      // phys block for frag reads

  for (int t = 0; t < ktiles; ++t) {
    const int k0 = kbase + t * 64;
    const unsigned short* gbase = isQ ? gQ : (gK + (size_t)k0 * DIM);

    // ---- stage chunk 0 ----
    bf16x8 g[4];
#pragma unroll
    for (int i = 0; i < 4; ++i)
      if (i < ninst)
        g[i] = *(const bf16x8*)(gbase + (size_t)(rbase + i * 16 + sr) * DIM + jblk * 8);
#pragma unroll
    for (int i = 0; i < 4; ++i)
      if (i < ninst)
        *(bf16x8*)&stage[0][plane_off + (rbase + i * 16 + sr) * 32 + scm * 8] = g[i];
    __syncthreads();

    // ---- S = Q K^T over 16 chunks of 32-d, double-buffered ----
    f32x4 sa[2][2] = {};
    for (int c = 0; c < 16; ++c) {
      const int bsel = c & 1;
      if (c < 15) {
        const int d0 = (c + 1) * 32;
#pragma unroll
        for (int i = 0; i < 4; ++i)
          if (i < ninst)
            g[i] = *(const bf16x8*)(gbase + (size_t)(rbase + i * 16 + sr) * DIM + d0 + jblk * 8);
      }
      const short* st = stage[bsel];
      bf16x8 a0h = *(const bf16x8*)&st[((qsp + 0) * 16 + l15) * 32 + pb];
      bf16x8 a1h = *(const bf16x8*)&st[((qsp + 1) * 16 + l15) * 32 + pb];
      bf16x8 a0l = *(const bf16x8*)&st[4096 + ((qsp + 0) * 16 + l15) * 32 + pb];
      bf16x8 a1l = *(const bf16x8*)&st[4096 + ((qsp + 1) * 16 + l15) * 32 + pb];
      bf16x8 b0h = *(const bf16x8*)&st[8192 + ((ksp + 0) * 16 + l15) * 32 + pb];
      bf16x8 b1h = *(const bf16x8*)&st[8192 + ((ksp + 1) * 16 + l15) * 32 + pb];
      bf16x8 b0l = *(const bf16x8*)&st[10240 + ((ksp + 0) * 16 + l15) * 32 + pb];
      bf16x8 b1l = *(const bf16x8*)&st[10240 + ((ksp + 1) * 16 + l15) * 32 + pb];
      sa[0][0] = __builtin_amdgcn_mfma_f32_16x16x32_bf16(a0h, b0h, sa[0][0], 0, 0, 0);
      sa[0][0] = __builtin_amdgcn_mfma_f32_16x16x32_bf16(a0h, b0l, sa[0][0], 0, 0, 0);
      sa[0][0] = __builtin_amdgcn_mfma_f32_16x16x32_bf16(a0l, b0h, sa[0][0], 0, 0, 0);
      sa[0][1] = __builtin_amdgcn_mfma_f32_16x16x32_bf16(a0h, b1h, sa[0][1], 0, 0, 0);
      sa[0][1] = __builtin_amdgcn_mfma_f32_16x16x32_bf16(a0h, b1l, sa[0][1], 0, 0, 0);
      sa[0][1] = __builtin_amdgcn_mfma_f32_16x16x32_bf16(a0l, b1h, sa[0][1], 0, 0, 0);
      sa[1][0] = __builtin_amdgcn_mfma_f32_16x16x32_bf16(a1h, b0h, sa[1][0], 0, 0, 0);
      sa[1][0] = __builtin_amdgcn_mfma_f32_16x16x32_bf16(a1h, b0l, sa[1][0], 0, 0, 0);
      sa[1][0] = __builtin_amdgcn_mfma_f32_16x16x32_bf16(a1l, b0h, sa[1][0], 0, 0, 0);
      sa[1][1] = __builtin_amdgcn_mfma_f32_16x16x32_bf16(a1h, b1h, sa[1][1], 0, 0, 0);
      sa[1][1] = __builtin_amdgcn_mfma_f32_16x16x32_bf16(a1h, b1l, sa[1][1], 0, 0, 0);
      sa[1][1] = __builtin_amdgcn_mfma_f32_16x16x32_bf16(a1l, b1h, sa[1][1], 0, 0, 0);
      if (c < 15) {
#pragma unroll
        for (int i = 0; i < 4; ++i)
          if (i < ninst)
            *(bf16x8*)&stage[1 - bsel][plane_off + (rbase + i * 16 + sr) * 32 + scm * 8] = g[i];
      }
      __syncthreads();
    }

    // ---- row-max partials ----
    float pm[2][4];
#pragma unroll
    for (int qi = 0; qi < 2; ++qi)
#pragma unroll
      for (int r = 0; r < 4; ++r) {
        float v = fmaxf(sa[qi][0][r], sa[qi][1][r]);
#pragma unroll
        for (int off = 1; off < 16; off <<= 1)
          v = fmaxf(v, __shfl_xor(v, off, 64));
        pm[qi][r] = v;
      }
    if (l15 == 0) {
#pragma unroll
      for (int qi = 0; qi < 2; ++qi)
#pragma unroll
        for (int r = 0; r < 4; ++r)
          red1[(qsp + qi) * 16 + quad * 4 + r][w >> 2] = pm[qi][r];
    }
    __syncthreads();  // B1
    if (tid < 128) {
      float mo = m_s[tid];
      float mn = fmaxf(mo, fmaxf(red1[tid][0], red1[tid][1]));
      m_s[tid] = mn;
      al_s[tid] = __expf(mo - mn);
    }
    __syncthreads();  // B2

    // ---- exp + P(hi) to LDS + row sums ----
#pragma unroll
    for (int qi = 0; qi < 2; ++qi)
#pragma unroll
      for (int r = 0; r < 4; ++r) {
        const int row = (qsp + qi) * 16 + quad * 4 + r;
        const float m = m_s[row];
        float p0 = __expf(sa[qi][0][r] - m);
        float p1 = __expf(sa[qi][1][r] - m);
        PsH[row][ksp * 16 + l15] = f2bf(p0);
        PsH[row][(ksp + 1) * 16 + l15] = f2bf(p1);
        float v = p0 + p1;
#pragma unroll
        for (int off = 1; off < 16; off <<= 1)
          v += __shfl_xor(v, off, 64);
        if (l15 == 0) red2[row][w >> 2] = v;
      }
    __syncthreads();  // B3
    if (tid < 128) l_s[tid] = l_s[tid] * al_s[tid] + red2[tid][0] + red2[tid][1];

    // ---- O = O*alpha + P @ x (single-term); wave owns d-slice w*64 ----
    float alv[8][4];
#pragma unroll
    for (int qt = 0; qt < 8; ++qt)
#pragma unroll
      for (int r = 0; r < 4; ++r)
        alv[qt][r] = al_s[qt * 16 + quad * 4 + r];
#pragma unroll
    for (int qt = 0; qt < 8; ++qt)
#pragma unroll
      for (int nt = 0; nt < 4; ++nt)
#pragma unroll
        for (int r = 0; r < 4; ++r)
          Of[qt][nt][r] *= alv[qt][r];
#pragma unroll
    for (int ks = 0; ks < 2; ++ks) {
      bf16x8 Ph[8];
#pragma unroll
      for (int qt = 0; qt < 8; ++qt)
        Ph[qt] = *(const bf16x8*)&PsH[qt * 16 + l15][ks * 32 + quad * 8];
      bf16x8 xf[4];
#pragma unroll
      for (int nt = 0; nt < 4; ++nt) {
        const size_t xo =
            ((size_t)(b * DIM + w * 64 + nt * 16 + l15)) * SEQ + k0 + ks * 32 + quad * 8;
        xf[nt] = *(const bf16x8*)(Xth + xo);
      }
#pragma unroll
      for (int nt = 0; nt < 4; ++nt)
#pragma unroll
        for (int qt = 0; qt < 8; ++qt)
          Of[qt][nt] = __builtin_amdgcn_mfma_f32_16x16x32_bf16(Ph[qt], xf[nt], Of[qt][nt], 0, 0, 0);
    }
    // no tile-end barrier needed: next tile's chunk barriers protect reuse
  }

  __syncthreads();
  if (gridDim.z == 1) {
#pragma unroll
    for (int qt = 0; qt < 8; ++qt)
#pragma unroll
      for (int r = 0; r < 4; ++r) {
        const float inv = 1.0f / l_s[qt * 16 + quad * 4 + r];
        const size_t ro = ((size_t)(b * SEQ + q0 + qt * 16 + quad * 4 + r)) * DIM + w * 64;
#pragma unroll
        for (int nt = 0; nt < 4; ++nt)
          out[ro + nt * 16 + l15] = Of[qt][nt][r] * inv;
      }
  } else {
    const size_t NE = (size_t)BATCH * SEQ * DIM;
    float* Ob = Opart + (size_t)blockIdx.z * NE;
#pragma unroll
    for (int qt = 0; qt < 8; ++qt)
#pragma unroll
      for (int r = 0; r < 4; ++r) {
        const size_t ro = ((size_t)(b * SEQ + q0 + qt * 16 + quad * 4 + r)) * DIM + w * 64;
#pragma unroll
        for (int nt = 0; nt < 4; ++nt)
          Ob[ro + nt * 16 + l15] = Of[qt][nt][r];
      }
    if (tid < 128) {
      size_t ri = (size_t)blockIdx.z * (BATCH * SEQ) + (size_t)b * SEQ + q0 + tid;
      Mp[ri] = m_s[tid];
      Lp[ri] = l_s[tid];
    }
  }
}

// ---------------------------------------------------------------------------
// Merge two split-K partials: out = (a0*O0 + a1*O1) / (a0*l0 + a1*l1).
// ---------------------------------------------------------------------------
__global__ __launch_bounds__(256) void merge_kernel(
    const float* __restrict__ Op, const float* __restrict__ Mp,
    const float* __restrict__ Lp, float* __restrict__ out) {
  const size_t NE = (size_t)BATCH * SEQ * DIM;
  const int NR = BATCH * SEQ;
  size_t i4 = (size_t)blockIdx.x * 256 + threadIdx.x;
  size_t e = i4 * 4;
  int row = (int)(e >> 9);
  float m0 = Mp[row], m1 = Mp[NR + row];
  float l0 = Lp[row], l1 = Lp[NR + row];
  float m = fmaxf(m0, m1);
  float a0 = __expf(m0 - m), a1 = __expf(m1 - m);
  float inv = 1.0f / (a0 * l0 + a1 * l1);
  float4 o0 = *(const float4*)(Op + e);
  float4 o1 = *(const float4*)(Op + NE + e);
  float4 r;
  r.x = (a0 * o0.x + a1 * o1.x) * inv;
  r.y = (a0 * o0.y + a1 * o1.y) * inv;
  r.z = (a0 * o0.z + a1 * o1.z) * inv;
  r.w = (a0 * o0.w + a1 * o1.w) * inv;
  *(float4*)(out + e) = r;
}

// ---------------------------------------------------------------------------
extern "C" void kernel_launch(void* const* d_in, const int* in_sizes, int n_in,
                              void* d_out, int out_size, void* d_ws,
                              size_t ws_size, hipStream_t stream) {
  const float* x   = (const float*)d_in[0];
  const float* rot = (const float*)d_in[1];
  const float* ent = (const float*)d_in[2];
  float* out = (float*)d_out;

  const size_t NE = (size_t)BATCH * SEQ * DIM;  // 16,777,216
  unsigned short* qh  = (unsigned short*)d_ws;
  unsigned short* ql  = qh + NE;
  unsigned short* kh  = ql + NE;
  unsigned short* kl  = kh + NE;
  unsigned short* xth = kl + NE;
  unsigned short* wrh = xth + NE;
  unsigned short* wrl = wrh + 262144;
  unsigned short* weh = wrl + 262144;
  unsigned short* wel = weh + 262144;
  float* Opart = (float*)(wel + 262144);     // 2*NE floats if splits==2
  float* Mp    = Opart + 2 * NE;
  float* Lp    = Mp + 2 * (BATCH * SEQ);
  // xh/xl alias the Opart region (proj finishes before attn writes Opart)
  unsigned short* xh = (unsigned short*)Opart;
  unsigned short* xl = xh + NE;

  const size_t need2 =
      (5 * NE + 4 * 262144) * sizeof(unsigned short) +
      (2 * NE + 4 * (size_t)(BATCH * SEQ)) * sizeof(float);
  const int splits = (ws_size >= need2) ? 2 : 1;

  wt_split_kernel<<<128, 256, 0, stream>>>(rot, ent, wrh, wrl, weh, wel);
  x_split_kernel<<<(unsigned)(NE / 1024), 256, 0, stream>>>(x, xh, xl);
  xt_split_kernel<<<dim3(SEQ / 64, DIM / 64, BATCH), 256, 0, stream>>>(x, xth);
  proj_both<<<dim3(DIM / 64, BATCH * SEQ / 64), 256, 0, stream>>>(
      xh, xl, wrh, wrl, weh, wel, qh, ql, kh, kl);

  attn_mfma<<<dim3(SEQ / 128, BATCH, splits), 512, 0, stream>>>(
      qh, ql, kh, kl, xth, out, Opart, Mp, Lp);
  if (splits == 2) {
    merge_kernel<<<(unsigned)(NE / 1024), 256, 0, stream>>>(Opart, Mp, Lp, out);
  }
}

// Round 6
// 1678.217 us; speedup vs baseline: 2.7484x; 2.7484x over previous
//
#include <hip/hip_runtime.h>

#define BATCH 8
#define SEQ   4096
#define DIM   512

typedef __attribute__((ext_vector_type(8))) short bf16x8;
typedef __attribute__((ext_vector_type(4))) float f32x4;
typedef __attribute__((ext_vector_type(4))) unsigned short us16x4;

__device__ __forceinline__ unsigned short f2bf(float f) {
  unsigned int u = __float_as_uint(f);
  unsigned int r = (u + 0x7fffu + ((u >> 16) & 1u)) >> 16;
  return (unsigned short)r;
}
__device__ __forceinline__ float bf2f(unsigned short s) {
  return __uint_as_float(((unsigned int)s) << 16);
}

// ---------------------------------------------------------------------------
// Transpose + split weights: Wt[e][d] = W[d][e] (* scale for rotation).
// ---------------------------------------------------------------------------
__global__ __launch_bounds__(256) void wt_split_kernel(
    const float* __restrict__ rot, const float* __restrict__ ent,
    unsigned short* __restrict__ wrh, unsigned short* __restrict__ wrl,
    unsigned short* __restrict__ weh, unsigned short* __restrict__ wel) {
  const float scale = 0.04419417382415922f;  // 1/sqrt(512)
  int g = blockIdx.x * 256 + threadIdx.x;
  for (int idx = g; idx < 512 * 512; idx += 128 * 256) {
    int d = idx >> 9, e = idx & 511;
    size_t o = (size_t)e * 512 + d;
    float v = rot[idx] * scale;
    unsigned short h = f2bf(v);
    wrh[o] = h; wrl[o] = f2bf(v - bf2f(h));
    float v2 = ent[idx];
    unsigned short h2 = f2bf(v2);
    weh[o] = h2; wel[o] = f2bf(v2 - bf2f(h2));
  }
}

// ---------------------------------------------------------------------------
// Row-major split of x into bf16 hi/lo (for proj_both A-fragments).
// ---------------------------------------------------------------------------
__global__ __launch_bounds__(256) void x_split_kernel(
    const float* __restrict__ X, unsigned short* __restrict__ Xh,
    unsigned short* __restrict__ Xl) {
  size_t i = ((size_t)blockIdx.x * 256 + threadIdx.x) * 4;
  float4 v = *(const float4*)(X + i);
  us16x4 hh, ll;
  float vv[4] = {v.x, v.y, v.z, v.w};
#pragma unroll
  for (int e = 0; e < 4; ++e) {
    unsigned short h = f2bf(vv[e]);
    hh[e] = h;
    ll[e] = f2bf(vv[e] - bf2f(h));
  }
  *(us16x4*)(Xh + i) = hh;
  *(us16x4*)(Xl + i) = ll;
}

// ---------------------------------------------------------------------------
// Transpose x: Xt[b][d][n] = x[b][n][d], bf16 hi only (PV is single-term).
// ---------------------------------------------------------------------------
__global__ __launch_bounds__(256) void xt_split_kernel(
    const float* __restrict__ X, unsigned short* __restrict__ Th) {
  __shared__ float T[64][65];
  const int b = blockIdx.z, n0 = blockIdx.x * 64, d0 = blockIdx.y * 64;
  const int tid = threadIdx.x;
  for (int idx = tid; idx < 4096; idx += 256) {
    int r = idx >> 6, c = idx & 63;
    T[r][c] = X[((size_t)(b * SEQ + n0 + r)) * DIM + d0 + c];
  }
  __syncthreads();
  for (int idx = tid; idx < 4096; idx += 256) {
    int r = idx >> 6, c = idx & 63;  // r: d, c: n
    size_t o = ((size_t)(b * DIM + d0 + r)) * SEQ + n0 + c;
    Th[o] = f2bf(T[c][r]);
  }
}

// ---------------------------------------------------------------------------
// Fused projection: Q = X@rot*scale, K = X@ent via bf16-split MFMA (3 terms).
// A-fragments read directly from pre-split Xh/Xl.
// ---------------------------------------------------------------------------
__global__ __launch_bounds__(256, 2) void proj_both(
    const unsigned short* __restrict__ Xh, const unsigned short* __restrict__ Xl,
    const unsigned short* __restrict__ wrh, const unsigned short* __restrict__ wrl,
    const unsigned short* __restrict__ weh, const unsigned short* __restrict__ wel,
    unsigned short* __restrict__ qh, unsigned short* __restrict__ ql,
    unsigned short* __restrict__ kh, unsigned short* __restrict__ kl) {
  const int tid = threadIdx.x;
  const int w = tid >> 6, lane = tid & 63, l15 = lane & 15, quad = lane >> 4;
  const int rowBase = blockIdx.y * 64 + (w & 1) * 32;
  const int colBase = blockIdx.x * 64 + (w >> 1) * 32;
  f32x4 qa[2][2] = {}, ka[2][2] = {};
  size_t xo[2];
  const unsigned short *rh[2], *rl[2], *eh[2], *el[2];
  xo[0] = (size_t)(rowBase + l15) * DIM + quad * 8;
  xo[1] = (size_t)(rowBase + 16 + l15) * DIM + quad * 8;
#pragma unroll
  for (int ni = 0; ni < 2; ++ni) {
    size_t o = (size_t)(colBase + ni * 16 + l15) * DIM + quad * 8;
    rh[ni] = wrh + o; rl[ni] = wrl + o; eh[ni] = weh + o; el[ni] = wel + o;
  }
  for (int d0 = 0; d0 < DIM; d0 += 32) {
    bf16x8 ah[2], al[2];
#pragma unroll
    for (int mi = 0; mi < 2; ++mi) {
      ah[mi] = *(const bf16x8*)(Xh + xo[mi] + d0);
      al[mi] = *(const bf16x8*)(Xl + xo[mi] + d0);
    }
#pragma unroll
    for (int ni = 0; ni < 2; ++ni) {
      bf16x8 bh = *(const bf16x8*)(rh[ni] + d0);
      bf16x8 bl = *(const bf16x8*)(rl[ni] + d0);
      bf16x8 ch = *(const bf16x8*)(eh[ni] + d0);
      bf16x8 cl = *(const bf16x8*)(el[ni] + d0);
#pragma unroll
      for (int mi = 0; mi < 2; ++mi) {
        qa[mi][ni] = __builtin_amdgcn_mfma_f32_16x16x32_bf16(ah[mi], bh, qa[mi][ni], 0, 0, 0);
        qa[mi][ni] = __builtin_amdgcn_mfma_f32_16x16x32_bf16(ah[mi], bl, qa[mi][ni], 0, 0, 0);
        qa[mi][ni] = __builtin_amdgcn_mfma_f32_16x16x32_bf16(al[mi], bh, qa[mi][ni], 0, 0, 0);
        ka[mi][ni] = __builtin_amdgcn_mfma_f32_16x16x32_bf16(ah[mi], ch, ka[mi][ni], 0, 0, 0);
        ka[mi][ni] = __builtin_amdgcn_mfma_f32_16x16x32_bf16(ah[mi], cl, ka[mi][ni], 0, 0, 0);
        ka[mi][ni] = __builtin_amdgcn_mfma_f32_16x16x32_bf16(al[mi], ch, ka[mi][ni], 0, 0, 0);
      }
    }
  }
#pragma unroll
  for (int mi = 0; mi < 2; ++mi)
#pragma unroll
    for (int ni = 0; ni < 2; ++ni)
#pragma unroll
      for (int r = 0; r < 4; ++r) {
        int row = rowBase + mi * 16 + quad * 4 + r;
        int col = colBase + ni * 16 + l15;
        size_t o = (size_t)row * DIM + col;
        float v = qa[mi][ni][r];
        unsigned short h = f2bf(v);
        qh[o] = h; ql[o] = f2bf(v - bf2f(h));
        float v2 = ka[mi][ni][r];
        unsigned short h2 = f2bf(v2);
        kh[o] = h2; kl[o] = f2bf(v2 - bf2f(h2));
      }
}

// ---------------------------------------------------------------------------
// Flash attention. BQ=128, BK=64, 512 threads (8 waves).
// __launch_bounds__(512, 2): 256-reg budget -> NO accumulator spill.
// S-stage: wave w -> q-subs {2(w&3),+1}, k-subs {2(w>>2),+1}.
// Staging: Qh/Ql 128x32, Kh/Kl 64x32 per 32-d chunk, double-buffered,
// swizzle swz=(r>>1)&3 (2-way max = free). 1 barrier per chunk.
// PV: wave w owns d-slice [w*64, w*64+64), single-term P@x.
// Split-K via gridDim.z; merge_kernel combines.
// ---------------------------------------------------------------------------
__global__ __launch_bounds__(512, 2) void attn_mfma(
    const unsigned short* __restrict__ Qh, const unsigned short* __restrict__ Ql,
    const unsigned short* __restrict__ Kh, const unsigned short* __restrict__ Kl,
    const unsigned short* __restrict__ Xth, float* __restrict__ out,
    float* __restrict__ Opart, float* __restrict__ Mp, float* __restrict__ Lp) {
  // buffer layout (shorts): Qh[0..4095] Ql[4096..8191] Kh[8192..10239] Kl[10240..12287]
  __shared__ short stage[2][12288];        // 48 KiB
  __shared__ unsigned short PsH[128][72];  // 18 KiB
  __shared__ float red1[128][2], red2[128][2];
  __shared__ float m_s[128], l_s[128], al_s[128];

  const int tid = threadIdx.x;
  const int w = tid >> 6, lane = tid & 63, l15 = lane & 15, quad = lane >> 4;
  const int b = blockIdx.y, q0 = blockIdx.x * 128;
  const int qsp = (w & 3) * 2, ksp = (w >> 2) * 2;
  const int ktiles = (SEQ / 64) / gridDim.z;
  const int kbase = blockIdx.z * ktiles * 64;

  if (tid < 128) { m_s[tid] = -3.0e38f; l_s[tid] = 0.0f; }
  __syncthreads();

  f32x4 Of[8][4] = {};

  // staging geometry
  const int sr = lane >> 2, scm = lane & 3;
  const int jblk = scm ^ ((sr >> 1) & 3);            // logical 16B block to load
  const bool isQ = (w < 4);
  const int rbase = isQ ? (w & 1) * 64 : ((w >> 1) & 1) * 32;
  const int ninst = isQ ? 4 : 2;
  const int plane_off = isQ ? ((w >> 1) & 1) * 4096 : 8192 + (w & 1) * 2048;
  const unsigned short* gQ = (((w >> 1) & 1) ? Ql : Qh) + (size_t)(b * SEQ + q0) * DIM;
  const unsigned short* gK = ((w & 1) ? Kl : Kh) + (size_t)b * SEQ * DIM;
  const int pb = (quad ^ ((l15 >> 1) & 3)) * 8;      // phys block for frag reads

  for (int t = 0; t < ktiles; ++t) {
    const int k0 = kbase + t * 64;
    const unsigned short* gbase = isQ ? gQ : (gK + (size_t)k0 * DIM);

    // ---- stage chunk 0 ----
    bf16x8 g[4];
#pragma unroll
    for (int i = 0; i < 4; ++i)
      if (i < ninst)
        g[i] = *(const bf16x8*)(gbase + (size_t)(rbase + i * 16 + sr) * DIM + jblk * 8);
#pragma unroll
    for (int i = 0; i < 4; ++i)
      if (i < ninst)
        *(bf16x8*)&stage[0][plane_off + (rbase + i * 16 + sr) * 32 + scm * 8] = g[i];
    __syncthreads();

    // ---- S = Q K^T over 16 chunks of 32-d, double-buffered ----
    f32x4 sa[2][2] = {};
    for (int c = 0; c < 16; ++c) {
      const int bsel = c & 1;
      if (c < 15) {
        const int d0 = (c + 1) * 32;
#pragma unroll
        for (int i = 0; i < 4; ++i)
          if (i < ninst)
            g[i] = *(const bf16x8*)(gbase + (size_t)(rbase + i * 16 + sr) * DIM + d0 + jblk * 8);
      }
      const short* st = stage[bsel];
      bf16x8 a0h = *(const bf16x8*)&st[((qsp + 0) * 16 + l15) * 32 + pb];
      bf16x8 a1h = *(const bf16x8*)&st[((qsp + 1) * 16 + l15) * 32 + pb];
      bf16x8 a0l = *(const bf16x8*)&st[4096 + ((qsp + 0) * 16 + l15) * 32 + pb];
      bf16x8 a1l = *(const bf16x8*)&st[4096 + ((qsp + 1) * 16 + l15) * 32 + pb];
      bf16x8 b0h = *(const bf16x8*)&st[8192 + ((ksp + 0) * 16 + l15) * 32 + pb];
      bf16x8 b1h = *(const bf16x8*)&st[8192 + ((ksp + 1) * 16 + l15) * 32 + pb];
      bf16x8 b0l = *(const bf16x8*)&st[10240 + ((ksp + 0) * 16 + l15) * 32 + pb];
      bf16x8 b1l = *(const bf16x8*)&st[10240 + ((ksp + 1) * 16 + l15) * 32 + pb];
      sa[0][0] = __builtin_amdgcn_mfma_f32_16x16x32_bf16(a0h, b0h, sa[0][0], 0, 0, 0);
      sa[0][0] = __builtin_amdgcn_mfma_f32_16x16x32_bf16(a0h, b0l, sa[0][0], 0, 0, 0);
      sa[0][0] = __builtin_amdgcn_mfma_f32_16x16x32_bf16(a0l, b0h, sa[0][0], 0, 0, 0);
      sa[0][1] = __builtin_amdgcn_mfma_f32_16x16x32_bf16(a0h, b1h, sa[0][1], 0, 0, 0);
      sa[0][1] = __builtin_amdgcn_mfma_f32_16x16x32_bf16(a0h, b1l, sa[0][1], 0, 0, 0);
      sa[0][1] = __builtin_amdgcn_mfma_f32_16x16x32_bf16(a0l, b1h, sa[0][1], 0, 0, 0);
      sa[1][0] = __builtin_amdgcn_mfma_f32_16x16x32_bf16(a1h, b0h, sa[1][0], 0, 0, 0);
      sa[1][0] = __builtin_amdgcn_mfma_f32_16x16x32_bf16(a1h, b0l, sa[1][0], 0, 0, 0);
      sa[1][0] = __builtin_amdgcn_mfma_f32_16x16x32_bf16(a1l, b0h, sa[1][0], 0, 0, 0);
      sa[1][1] = __builtin_amdgcn_mfma_f32_16x16x32_bf16(a1h, b1h, sa[1][1], 0, 0, 0);
      sa[1][1] = __builtin_amdgcn_mfma_f32_16x16x32_bf16(a1h, b1l, sa[1][1], 0, 0, 0);
      sa[1][1] = __builtin_amdgcn_mfma_f32_16x16x32_bf16(a1l, b1h, sa[1][1], 0, 0, 0);
      if (c < 15) {
#pragma unroll
        for (int i = 0; i < 4; ++i)
          if (i < ninst)
            *(bf16x8*)&stage[1 - bsel][plane_off + (rbase + i * 16 + sr) * 32 + scm * 8] = g[i];
      }
      __syncthreads();
    }

    // ---- row-max partials ----
    float pm[2][4];
#pragma unroll
    for (int qi = 0; qi < 2; ++qi)
#pragma unroll
      for (int r = 0; r < 4; ++r) {
        float v = fmaxf(sa[qi][0][r], sa[qi][1][r]);
#pragma unroll
        for (int off = 1; off < 16; off <<= 1)
          v = fmaxf(v, __shfl_xor(v, off, 64));
        pm[qi][r] = v;
      }
    if (l15 == 0) {
#pragma unroll
      for (int qi = 0; qi < 2; ++qi)
#pragma unroll
        for (int r = 0; r < 4; ++r)
          red1[(qsp + qi) * 16 + quad * 4 + r][w >> 2] = pm[qi][r];
    }
    __syncthreads();  // B1
    if (tid < 128) {
      float mo = m_s[tid];
      float mn = fmaxf(mo, fmaxf(red1[tid][0], red1[tid][1]));
      m_s[tid] = mn;
      al_s[tid] = __expf(mo - mn);
    }
    __syncthreads();  // B2

    // ---- exp + P(hi) to LDS + row sums ----
#pragma unroll
    for (int qi = 0; qi < 2; ++qi)
#pragma unroll
      for (int r = 0; r < 4; ++r) {
        const int row = (qsp + qi) * 16 + quad * 4 + r;
        const float m = m_s[row];
        float p0 = __expf(sa[qi][0][r] - m);
        float p1 = __expf(sa[qi][1][r] - m);
        PsH[row][ksp * 16 + l15] = f2bf(p0);
        PsH[row][(ksp + 1) * 16 + l15] = f2bf(p1);
        float v = p0 + p1;
#pragma unroll
        for (int off = 1; off < 16; off <<= 1)
          v += __shfl_xor(v, off, 64);
        if (l15 == 0) red2[row][w >> 2] = v;
      }
    __syncthreads();  // B3
    if (tid < 128) l_s[tid] = l_s[tid] * al_s[tid] + red2[tid][0] + red2[tid][1];

    // ---- O = O*alpha + P @ x (single-term); wave owns d-slice w*64 ----
    float alv[8][4];
#pragma unroll
    for (int qt = 0; qt < 8; ++qt)
#pragma unroll
      for (int r = 0; r < 4; ++r)
        alv[qt][r] = al_s[qt * 16 + quad * 4 + r];
#pragma unroll
    for (int qt = 0; qt < 8; ++qt)
#pragma unroll
      for (int nt = 0; nt < 4; ++nt)
#pragma unroll
        for (int r = 0; r < 4; ++r)
          Of[qt][nt][r] *= alv[qt][r];
#pragma unroll
    for (int ks = 0; ks < 2; ++ks) {
      bf16x8 Ph[8];
#pragma unroll
      for (int qt = 0; qt < 8; ++qt)
        Ph[qt] = *(const bf16x8*)&PsH[qt * 16 + l15][ks * 32 + quad * 8];
      bf16x8 xf[4];
#pragma unroll
      for (int nt = 0; nt < 4; ++nt) {
        const size_t xo =
            ((size_t)(b * DIM + w * 64 + nt * 16 + l15)) * SEQ + k0 + ks * 32 + quad * 8;
        xf[nt] = *(const bf16x8*)(Xth + xo);
      }
#pragma unroll
      for (int nt = 0; nt < 4; ++nt)
#pragma unroll
        for (int qt = 0; qt < 8; ++qt)
          Of[qt][nt] = __builtin_amdgcn_mfma_f32_16x16x32_bf16(Ph[qt], xf[nt], Of[qt][nt], 0, 0, 0);
    }
    // no tile-end barrier needed: next tile's chunk barriers protect reuse
  }

  __syncthreads();
  if (gridDim.z == 1) {
#pragma unroll
    for (int qt = 0; qt < 8; ++qt)
#pragma unroll
      for (int r = 0; r < 4; ++r) {
        const float inv = 1.0f / l_s[qt * 16 + quad * 4 + r];
        const size_t ro = ((size_t)(b * SEQ + q0 + qt * 16 + quad * 4 + r)) * DIM + w * 64;
#pragma unroll
        for (int nt = 0; nt < 4; ++nt)
          out[ro + nt * 16 + l15] = Of[qt][nt][r] * inv;
      }
  } else {
    const size_t NE = (size_t)BATCH * SEQ * DIM;
    float* Ob = Opart + (size_t)blockIdx.z * NE;
#pragma unroll
    for (int qt = 0; qt < 8; ++qt)
#pragma unroll
      for (int r = 0; r < 4; ++r) {
        const size_t ro = ((size_t)(b * SEQ + q0 + qt * 16 + quad * 4 + r)) * DIM + w * 64;
#pragma unroll
        for (int nt = 0; nt < 4; ++nt)
          Ob[ro + nt * 16 + l15] = Of[qt][nt][r];
      }
    if (tid < 128) {
      size_t ri = (size_t)blockIdx.z * (BATCH * SEQ) + (size_t)b * SEQ + q0 + tid;
      Mp[ri] = m_s[tid];
      Lp[ri] = l_s[tid];
    }
  }
}

// ---------------------------------------------------------------------------
// Merge two split-K partials: out = (a0*O0 + a1*O1) / (a0*l0 + a1*l1).
// ---------------------------------------------------------------------------
__global__ __launch_bounds__(256) void merge_kernel(
    const float* __restrict__ Op, const float* __restrict__ Mp,
    const float* __restrict__ Lp, float* __restrict__ out) {
  const size_t NE = (size_t)BATCH * SEQ * DIM;
  const int NR = BATCH * SEQ;
  size_t i4 = (size_t)blockIdx.x * 256 + threadIdx.x;
  size_t e = i4 * 4;
  int row = (int)(e >> 9);
  float m0 = Mp[row], m1 = Mp[NR + row];
  float l0 = Lp[row], l1 = Lp[NR + row];
  float m = fmaxf(m0, m1);
  float a0 = __expf(m0 - m), a1 = __expf(m1 - m);
  float inv = 1.0f / (a0 * l0 + a1 * l1);
  float4 o0 = *(const float4*)(Op + e);
  float4 o1 = *(const float4*)(Op + NE + e);
  float4 r;
  r.x = (a0 * o0.x + a1 * o1.x) * inv;
  r.y = (a0 * o0.y + a1 * o1.y) * inv;
  r.z = (a0 * o0.z + a1 * o1.z) * inv;
  r.w = (a0 * o0.w + a1 * o1.w) * inv;
  *(float4*)(out + e) = r;
}

// ---------------------------------------------------------------------------
extern "C" void kernel_launch(void* const* d_in, const int* in_sizes, int n_in,
                              void* d_out, int out_size, void* d_ws,
                              size_t ws_size, hipStream_t stream) {
  const float* x   = (const float*)d_in[0];
  const float* rot = (const float*)d_in[1];
  const float* ent = (const float*)d_in[2];
  float* out = (float*)d_out;

  const size_t NE = (size_t)BATCH * SEQ * DIM;  // 16,777,216
  unsigned short* qh  = (unsigned short*)d_ws;
  unsigned short* ql  = qh + NE;
  unsigned short* kh  = ql + NE;
  unsigned short* kl  = kh + NE;
  unsigned short* xth = kl + NE;
  unsigned short* wrh = xth + NE;
  unsigned short* wrl = wrh + 262144;
  unsigned short* weh = wrl + 262144;
  unsigned short* wel = weh + 262144;
  float* Opart = (float*)(wel + 262144);     // 2*NE floats if splits==2
  float* Mp    = Opart + 2 * NE;
  float* Lp    = Mp + 2 * (BATCH * SEQ);
  // xh/xl alias the Opart region (proj finishes before attn writes Opart)
  unsigned short* xh = (unsigned short*)Opart;
  unsigned short* xl = xh + NE;

  const size_t need2 =
      (5 * NE + 4 * 262144) * sizeof(unsigned short) +
      (2 * NE + 4 * (size_t)(BATCH * SEQ)) * sizeof(float);
  const int splits = (ws_size >= need2) ? 2 : 1;

  wt_split_kernel<<<128, 256, 0, stream>>>(rot, ent, wrh, wrl, weh, wel);
  x_split_kernel<<<(unsigned)(NE / 1024), 256, 0, stream>>>(x, xh, xl);
  xt_split_kernel<<<dim3(SEQ / 64, DIM / 64, BATCH), 256, 0, stream>>>(x, xth);
  proj_both<<<dim3(DIM / 64, BATCH * SEQ / 64), 256, 0, stream>>>(
      xh, xl, wrh, wrl, weh, wel, qh, ql, kh, kl);

  attn_mfma<<<dim3(SEQ / 128, BATCH, splits), 512, 0, stream>>>(
      qh, ql, kh, kl, xth, out, Opart, Mp, Lp);
  if (splits == 2) {
    merge_kernel<<<(unsigned)(NE / 1024), 256, 0, stream>>>(Opart, Mp, Lp, out);
  }
}